// Round 8
// baseline (554.277 us; speedup 1.0000x reference)
//
#include <hip/hip_runtime.h>
#include <math.h>
#include <type_traits>

#define D    2048
#define DC   512
#define DR   64
#define NH   16
#define HD   128
#define Bb   2
#define Tt   2048
#define ROWS (Bb*Tt)   // 4096
#define LDX  2176      // row stride of q_ext / k_ext (2048 + 64 + 64 pad)

typedef __bf16 bf16x8 __attribute__((ext_vector_type(8)));
typedef __bf16 bf16x4 __attribute__((ext_vector_type(4)));
typedef float  f32x4  __attribute__((ext_vector_type(4)));
typedef float  f32x16 __attribute__((ext_vector_type(16)));
typedef unsigned int uint;

typedef const void __attribute__((address_space(1))) gvoid;
typedef void       __attribute__((address_space(3))) lvoid;

__device__ __forceinline__ void load_lds16(const void* g, void* l) {
    __builtin_amdgcn_global_load_lds((gvoid*)g, (lvoid*)l, 16, 0, 0);
}

// ============ bf16 MFMA GEMM: C = A[M,K] @ BT[N,K]^T, ldc variants =========
// Natural blockIdx order (R4: XCD swizzling thrashes L2 on this dispatch).
template <bool WF32, bool WBF16>
__global__ __launch_bounds__(256)
void gemm_bt(const __bf16* __restrict__ A, const __bf16* __restrict__ BT,
             float* __restrict__ Cf, __bf16* __restrict__ Cb,
             int M, int K, int ldcf, int ldcb) {
    __shared__ __bf16 As[128 * 32];
    __shared__ __bf16 Bs[128 * 32];

    const int tid  = threadIdx.x;
    const int w    = tid >> 6;
    const int lane = tid & 63;
    const int quad = lane >> 4;
    const int lc   = lane & 15;
    const int bm   = blockIdx.y * 128;
    const int bn   = blockIdx.x * 128;
    const int wm   = (w & 1) * 64;
    const int wn   = (w >> 1) * 64;

    const int sr = w * 32 + (lane >> 2);
    const int sc = (lane & 3) * 8;

    f32x4 acc[4][4] = {};

    for (int k0 = 0; k0 < K; k0 += 32) {
        const __bf16* ga = A  + (size_t)(bm + sr) * K + k0 + sc;
        const __bf16* gb = BT + (size_t)(bn + sr) * K + k0 + sc;
        load_lds16(ga,                  &As[(w * 32) * 32]);
        load_lds16(ga + (size_t)16 * K, &As[(w * 32 + 16) * 32]);
        load_lds16(gb,                  &Bs[(w * 32) * 32]);
        load_lds16(gb + (size_t)16 * K, &Bs[(w * 32 + 16) * 32]);
        __syncthreads();

        bf16x8 af[4], bfr[4];
        #pragma unroll
        for (int mi = 0; mi < 4; ++mi)
            af[mi] = *(bf16x8*)&As[(wm + mi * 16 + lc) * 32 + quad * 8];
        #pragma unroll
        for (int ni = 0; ni < 4; ++ni)
            bfr[ni] = *(bf16x8*)&Bs[(wn + ni * 16 + lc) * 32 + quad * 8];
        #pragma unroll
        for (int mi = 0; mi < 4; ++mi)
            #pragma unroll
            for (int ni = 0; ni < 4; ++ni)
                acc[mi][ni] = __builtin_amdgcn_mfma_f32_16x16x32_bf16(
                    af[mi], bfr[ni], acc[mi][ni], 0, 0, 0);
        __syncthreads();
    }

    #pragma unroll
    for (int mi = 0; mi < 4; ++mi)
        #pragma unroll
        for (int r = 0; r < 4; ++r) {
            const int row = bm + wm + mi * 16 + quad * 4 + r;
            const int col = bn + wn + lc;
            #pragma unroll
            for (int ni = 0; ni < 4; ++ni) {
                float v = acc[mi][ni][r];
                if constexpr (WF32)  Cf[(size_t)row * ldcf + col + ni * 16] = v;
                if constexpr (WBF16) Cb[(size_t)row * ldcb + col + ni * 16] = (__bf16)v;
            }
        }
}

// ============ fp32 -> bf16 convert =========================================
__global__ void f32_to_bf16(const float* __restrict__ in,
                            __bf16* __restrict__ out, int n) {
    int i = blockIdx.x * blockDim.x + threadIdx.x;
    if (i < n) out[i] = (__bf16)in[i];
}

// ============ transpose + convert: W[R][C] f32 -> WT[C][R] bf16 ============
__global__ __launch_bounds__(256)
void transpose_conv(const float* __restrict__ W, __bf16* __restrict__ WT,
                    int R, int C) {
    __shared__ float tile[64][65];
    const int r0 = blockIdx.x * 64;
    const int c0 = blockIdx.y * 64;
    const int tid = threadIdx.x;
    for (int e = tid; e < 64 * 64; e += 256) {
        int i = e >> 6, j = e & 63;
        tile[i][j] = W[(size_t)(r0 + i) * C + c0 + j];
    }
    __syncthreads();
    for (int e = tid; e < 64 * 64; e += 256) {
        int i = e >> 6, j = e & 63;
        WT[(size_t)(c0 + i) * R + r0 + j] = (__bf16)tile[j][i];
    }
}

// ============ RoPE in-place on ext-buffer cols 2048..2111 (bf16) ===========
__global__ void rope_ext(__bf16* __restrict__ p, float* __restrict__ ent) {
    int idx = blockIdx.x * blockDim.x + threadIdx.x;
    if (idx >= ROWS * 32) return;
    int row = idx >> 5;
    int i   = idx & 31;
    int t   = row & (Tt - 1);
    float inv  = powf(10000.0f, -(float)(2 * i) / 64.0f);
    float fr   = (float)t * inv;
    float c = cosf(fr), s = sinf(fr);
    __bf16* v = p + (size_t)row * LDX + 2048;
    float x1 = (float)v[i], x2 = (float)v[i + 32];
    float o1 = x1 * c - x2 * s;
    float o2 = x2 * c + x1 * s;
    v[i]      = (__bf16)o1;
    v[i + 32] = (__bf16)o2;
    if (ent) {
        ent[(size_t)row * 576 + 512 + i] = o1;
        ent[(size_t)row * 576 + 544 + i] = o2;
    }
}

// ============ V transpose: vb[B][T][D] -> vtb[B][D][T] (bf16) ==============
__global__ __launch_bounds__(256)
void transpose_v(const __bf16* __restrict__ vb, __bf16* __restrict__ vtb) {
    __shared__ __bf16 tile[64][65];
    const int t0 = blockIdx.x * 64;
    const int c0 = blockIdx.y * 64;
    const int b  = blockIdx.z;
    const int tid = threadIdx.x;
    for (int e = tid; e < 64 * 64; e += 256) {
        int i = e >> 6, j = e & 63;
        tile[i][j] = vb[((size_t)(b * Tt + t0 + i)) * D + c0 + j];
    }
    __syncthreads();
    for (int e = tid; e < 64 * 64; e += 256) {
        int i = e >> 6, j = e & 63;
        vtb[((size_t)(b * D + c0 + i)) * Tt + t0 + j] = tile[j][i];
    }
}

// ============ split-KV MFMA flash attention (R3 base + 2-deep prefetch) ====
// Q-tile = 128 queries (4 waves x 32 q each), KV tiles of 64 keys.
// S^T = K.Q^T via mfma_32x32x16 (lane owns ONE query: col = lane&31).
// P^T relayout via wave-private LDS PsT (full 64-key buffer, R3-proven).
// 2-TILE-DEEP register prefetch, explicit A/B sets (no runtime indexing):
// loads for tile t+2 issued during tile t -> load->consume window spans
// 2 compute phases (R3's 1-deep window is the suspected per-tile stall).
// Tile count per block is always EVEN (ntiles=2qt+2, t0=8sp) -> pair loop.
// LDS 62,464 B -> 2 blocks/CU (R3 locality regime). VGPR ~160 is free:
// LDS caps at 8 waves/CU, and 160 <= 256-VGPR 8-wave limit.
#define KS_STR 200         // 192 cols + pad; 400B row
#define VT_STR 72          // 64 cols + pad; 144B row
#define PS_STR 72          // 64 cols + pad; 144B row (wave-private P^T)
#define SPLIT_TILES 8

// packed partial-slot base for q-tile qt (ntiles = 2qt+2, splits of 8)
__device__ __forceinline__ int pbase_qt(int qt) {
    int a = qt >> 2, r = qt & 3;
    return qt + 2 * a * (a - 1) + r * a;
}

__global__ __launch_bounds__(256, 2)
void attn_split(const __bf16* __restrict__ qx, const __bf16* __restrict__ kx,
                const __bf16* __restrict__ vtb, __bf16* __restrict__ opart,
                float* __restrict__ mlpart) {
    const int qt = (Tt / 128 - 1) - (int)blockIdx.y;   // longest-first
    const int sp = blockIdx.x;
    const int t0 = sp * SPLIT_TILES;
    const int ntiles = 2 * qt + 2;
    if (t0 >= ntiles) return;                           // unused split slot
    const int tend = min(t0 + SPLIT_TILES, ntiles);     // tend - t0 is EVEN
    const int hb = blockIdx.z;
    const int h  = hb & (NH - 1);
    const int b  = hb >> 4;
    const int q0 = qt * 128;

    __shared__ __bf16 Ks[64][KS_STR];     // 25.6 KB (k cols 0..127, kr 128..191)
    __shared__ __bf16 Vt[128][VT_STR];    // 18.4 KB
    __shared__ __bf16 PsT[4][32][PS_STR]; // 18.4 KB wave-private P^T[q][key]

    const int tid    = threadIdx.x;
    const int w      = tid >> 6;
    const int lane   = tid & 63;
    const int lane31 = lane & 31;
    const int hi     = lane >> 5;
    const int hi8    = hi * 8;
    const int hi4    = hi * 4;

    // per-wave last tile actually needed (later tiles fully masked -> skip compute)
    const int qwmax = q0 + w * 32 + 31;
    const int tendw = min(tend, (qwmax >> 6) + 1);
    const int qglob = q0 + w * 32 + lane31;             // this lane's query

    // ---- Q fragments (B-operand: col = q = lane&31, k = hi*8+e per slice) ----
    bf16x8 aq[12];
    {
        const __bf16* qrow = qx + (size_t)(b * Tt + q0 + w * 32 + lane31) * LDX;
        #pragma unroll
        for (int kt = 0; kt < 8; ++kt)
            aq[kt] = *(const bf16x8*)(qrow + h * HD + kt * 16 + hi8);
        #pragma unroll
        for (int kt = 0; kt < 4; ++kt)
            aq[8 + kt] = *(const bf16x8*)(qrow + 2048 + kt * 16 + hi8);
    }

    // ---- staging geometry (K tile 64x192, V tile 128x64) ----
    int krow[6], kcol[6], kgo[6];
    #pragma unroll
    for (int j = 0; j < 6; ++j) {
        int c   = tid + j * 256;
        int row = c / 24, c24 = c - row * 24;
        krow[j] = row;
        kcol[j] = c24 * 8;
        kgo[j]  = row * LDX + ((c24 < 16) ? (h * HD + c24 * 8)
                                          : (2048 + (c24 - 16) * 8));
    }
    const int vrow = tid >> 3;
    const int vcol = (tid & 7) * 8;
    const __bf16* kb0 = kx + (size_t)b * Tt * LDX;
    const __bf16* vb0 = vtb + ((size_t)b * D + (size_t)h * HD) * Tt;

    // ---- 2-deep prefetch register sets (STATIC names, rule #20) ----
    bf16x8 pkA[6], pvA[4], pkB[6], pvB[4];
    {
        const __bf16* kbt = kb0 + (size_t)(t0 * 64) * LDX;
        const __bf16* vbt = vb0 + t0 * 64;
        #pragma unroll
        for (int j = 0; j < 6; ++j) pkA[j] = *(const bf16x8*)(kbt + kgo[j]);
        #pragma unroll
        for (int j = 0; j < 4; ++j)
            pvA[j] = *(const bf16x8*)(vbt + (vrow + j * 32) * Tt + vcol);
        const __bf16* kbt1 = kbt + (size_t)64 * LDX;
        const __bf16* vbt1 = vbt + 64;
        #pragma unroll
        for (int j = 0; j < 6; ++j) pkB[j] = *(const bf16x8*)(kbt1 + kgo[j]);
        #pragma unroll
        for (int j = 0; j < 4; ++j)
            pvB[j] = *(const bf16x8*)(vbt1 + (vrow + j * 32) * Tt + vcol);
    }

    float m_i = -1e30f, l_i = 0.f;      // per-lane: ONE query (lane&31)
    f32x16 Of[4] = {};                   // O^T: hd = nb*32 + crow(r,hi), q = lane&31

    const float rscale = 0.07216878364870323f;   // 1/sqrt(192)

    // ---- per-tile compute body (R3-proven, verbatim) ----
    auto compute_tile = [&](int it) {
        const int s0 = it * 64;
        // ---- S^T = K Q^T : st0/st1 cover keys {0..31},{32..63} ----
        f32x16 st0 = {}, st1 = {};
        __builtin_amdgcn_s_setprio(1);
        #pragma unroll
        for (int kt = 0; kt < 12; ++kt) {
            bf16x8 ak0 = *(bf16x8*)&Ks[lane31][kt * 16 + hi8];
            bf16x8 ak1 = *(bf16x8*)&Ks[32 + lane31][kt * 16 + hi8];
            st0 = __builtin_amdgcn_mfma_f32_32x32x16_bf16(ak0, aq[kt], st0, 0, 0, 0);
            st1 = __builtin_amdgcn_mfma_f32_32x32x16_bf16(ak1, aq[kt], st1, 0, 0, 0);
        }
        __builtin_amdgcn_s_setprio(0);

        // ---- scalarize + mask + tile max ----
        const bool dm = (s0 + 63 > q0 + w * 32);
        float sv0[16], sv1[16];
        float mt = -1e30f;
        #pragma unroll
        for (int r = 0; r < 16; ++r) {
            float a0 = st0[r] * rscale;
            float a1 = st1[r] * rscale;
            if (dm) {
                int kr = (r & 3) + 8 * (r >> 2) + hi4;
                if (s0 + kr > qglob)      a0 = -1e30f;
                if (s0 + 32 + kr > qglob) a1 = -1e30f;
            }
            sv0[r] = a0; sv1[r] = a1;
            mt = fmaxf(mt, fmaxf(a0, a1));
        }
        mt = fmaxf(mt, __shfl_xor(mt, 32, 64));

        // ---- always-rescale online softmax ----
        float mn = fmaxf(m_i, mt);
        float al = __expf(m_i - mn);
        m_i = mn;

        // ---- P^T -> wave-private LDS ----
        float rsum = 0.f;
        #pragma unroll
        for (int g = 0; g < 4; ++g) {
            bf16x4 pr;
            #pragma unroll
            for (int j = 0; j < 4; ++j) {
                __bf16 pb = (__bf16)__expf(sv0[g * 4 + j] - mn);
                pr[j] = pb;
                rsum += (float)pb;
            }
            *(bf16x4*)&PsT[w][lane31][g * 8 + hi4] = pr;
        }
        #pragma unroll
        for (int g = 0; g < 4; ++g) {
            bf16x4 pr;
            #pragma unroll
            for (int j = 0; j < 4; ++j) {
                __bf16 pb = (__bf16)__expf(sv1[g * 4 + j] - mn);
                pr[j] = pb;
                rsum += (float)pb;
            }
            *(bf16x4*)&PsT[w][lane31][32 + g * 8 + hi4] = pr;
        }
        rsum += __shfl_xor(rsum, 32, 64);
        l_i = l_i * al + rsum;
        #pragma unroll
        for (int nb = 0; nb < 4; ++nb) Of[nb] *= al;

        // ---- O^T += Vt P^T ----
        __builtin_amdgcn_s_setprio(1);
        #pragma unroll
        for (int kblk = 0; kblk < 4; ++kblk) {
            bf16x8 bp = *(bf16x8*)&PsT[w][lane31][kblk * 16 + hi8];
            #pragma unroll
            for (int nb = 0; nb < 4; ++nb) {
                bf16x8 av = *(bf16x8*)&Vt[nb * 32 + lane31][kblk * 16 + hi8];
                Of[nb] = __builtin_amdgcn_mfma_f32_32x32x16_bf16(av, bp, Of[nb], 0, 0, 0);
            }
        }
        __builtin_amdgcn_s_setprio(0);
    };

    for (int it = t0; it < tend; it += 2) {
        // ======== tile it (buffer A) ========
        __syncthreads();
        #pragma unroll
        for (int j = 0; j < 6; ++j) *(bf16x8*)&Ks[krow[j]][kcol[j]] = pkA[j];
        #pragma unroll
        for (int j = 0; j < 4; ++j) *(bf16x8*)&Vt[vrow + j * 32][vcol] = pvA[j];
        __syncthreads();
        if (it + 2 < tend) {                 // prefetch tile it+2 into A
            const __bf16* kbn = kb0 + (size_t)((it + 2) * 64) * LDX;
            const __bf16* vbn = vb0 + (it + 2) * 64;
            #pragma unroll
            for (int j = 0; j < 6; ++j) pkA[j] = *(const bf16x8*)(kbn + kgo[j]);
            #pragma unroll
            for (int j = 0; j < 4; ++j)
                pvA[j] = *(const bf16x8*)(vbn + (vrow + j * 32) * Tt + vcol);
        }
        if (it < tendw) compute_tile(it);

        // ======== tile it+1 (buffer B) ========
        __syncthreads();
        #pragma unroll
        for (int j = 0; j < 6; ++j) *(bf16x8*)&Ks[krow[j]][kcol[j]] = pkB[j];
        #pragma unroll
        for (int j = 0; j < 4; ++j) *(bf16x8*)&Vt[vrow + j * 32][vcol] = pvB[j];
        __syncthreads();
        if (it + 3 < tend) {                 // prefetch tile it+3 into B
            const __bf16* kbn = kb0 + (size_t)((it + 3) * 64) * LDX;
            const __bf16* vbn = vb0 + (it + 3) * 64;
            #pragma unroll
            for (int j = 0; j < 6; ++j) pkB[j] = *(const bf16x8*)(kbn + kgo[j]);
            #pragma unroll
            for (int j = 0; j < 4; ++j)
                pvB[j] = *(const bf16x8*)(vbn + (vrow + j * 32) * Tt + vcol);
        }
        if (it + 1 < tendw) compute_tile(it + 1);
    }

    // ---- write partials: O row q = w*32+lane31, cols hd = nb*32 + g*8 + hi*4 + j ----
    const int p = hb * 40 + pbase_qt(qt) + sp;
    __bf16* ob = opart + (size_t)p * (128 * 128) + (size_t)(w * 32 + lane31) * 128;
    #pragma unroll
    for (int nb = 0; nb < 4; ++nb)
        #pragma unroll
        for (int g = 0; g < 4; ++g) {
            bf16x4 o4;
            #pragma unroll
            for (int j = 0; j < 4; ++j) o4[j] = (__bf16)Of[nb][g * 4 + j];
            *(bf16x4*)(ob + nb * 32 + g * 8 + hi4) = o4;
        }
    if (hi == 0) {
        mlpart[(size_t)p * 256 + w * 32 + lane31]       = m_i;
        mlpart[(size_t)p * 256 + 128 + w * 32 + lane31] = l_i;
    }
}

// ============ combine split partials -> aob (bf16) =========================
__global__ __launch_bounds__(256)
void attn_reduce(const __bf16* __restrict__ opart, const float* __restrict__ mlpart,
                 __bf16* __restrict__ aob) {
    const int qt = blockIdx.x;                // 0..15 (q-tiles of 128)
    const int hb = blockIdx.y;
    const int h  = hb & (NH - 1);
    const int b  = hb >> 4;
    const int nsp = (qt >> 2) + 1;
    const int p0  = hb * 40 + pbase_qt(qt);
    const int tid = threadIdx.x;
    const int ql  = tid >> 1;                 // 0..127
    const int cg  = (tid & 1) * 64;

    float M = -1e30f;
    for (int s = 0; s < nsp; ++s)
        M = fmaxf(M, mlpart[(size_t)(p0 + s) * 256 + ql]);
    float L = 0.f;
    float acc[64];
    #pragma unroll
    for (int j = 0; j < 64; ++j) acc[j] = 0.f;
    for (int s = 0; s < nsp; ++s) {
        float ms = mlpart[(size_t)(p0 + s) * 256 + ql];
        float ls = mlpart[(size_t)(p0 + s) * 256 + 128 + ql];
        float sc = __expf(ms - M);
        L += ls * sc;
        const __bf16* op = opart + (size_t)(p0 + s) * (128 * 128) + (size_t)ql * 128 + cg;
        #pragma unroll
        for (int j8 = 0; j8 < 8; ++j8) {
            bf16x8 v = *(const bf16x8*)(op + j8 * 8);
            #pragma unroll
            for (int e = 0; e < 8; ++e) acc[j8 * 8 + e] += sc * (float)v[e];
        }
    }
    float invL = 1.0f / L;
    __bf16* outp = aob + ((size_t)(b * Tt + qt * 128 + ql)) * D + h * HD + cg;
    #pragma unroll
    for (int j8 = 0; j8 < 8; ++j8) {
        bf16x8 v;
        #pragma unroll
        for (int e = 0; e < 8; ++e) v[e] = (__bf16)(acc[j8 * 8 + e] * invL);
        *(bf16x8*)(outp + j8 * 8) = v;
    }
}

extern "C" void kernel_launch(void* const* d_in, const int* in_sizes, int n_in,
                              void* d_out, int out_size, void* d_ws, size_t ws_size,
                              hipStream_t stream) {
    const float* x    = (const float*)d_in[0];
    const float* Wkv  = (const float*)d_in[1];
    const float* Wkup = (const float*)d_in[2];
    const float* Wvup = (const float*)d_in[3];
    const float* Wq   = (const float*)d_in[4];
    const float* Wqr  = (const float*)d_in[5];
    const float* Wkr  = (const float*)d_in[6];
    const float* Wo   = (const float*)d_in[7];

    float* out0 = (float*)d_out;                     // (4096, 2048)
    float* out1 = out0 + (size_t)ROWS * D;           // (4096, 576) entry

    // ---- persistent buffers ----
    char* wsb = (char*)d_ws;
    __bf16* qext = (__bf16*)wsb;  wsb += (size_t)ROWS * LDX * 2;   // 17.8 MB
    __bf16* kext = (__bf16*)wsb;  wsb += (size_t)ROWS * LDX * 2;   // 17.8 MB
    __bf16* vtb  = (__bf16*)wsb;  wsb += (size_t)ROWS * D   * 2;   // 16.8 MB
    __bf16* aob  = (__bf16*)wsb;  wsb += (size_t)ROWS * D   * 2;   // 16.8 MB
    __bf16* WoT  = (__bf16*)wsb;  wsb += (size_t)D * D * 2;        //  8.4 MB

    // ---- phase-1 scratch (dead before attention) / attention partials ----
    char* scratch = wsb;
    __bf16* xb    = (__bf16*)scratch;                        // 16.8 MB
    __bf16* vb    = (__bf16*)(scratch + 16777216);           // 16.8 MB
    __bf16* ckvb  = (__bf16*)(scratch + 33554432);           //  4.2 MB
    __bf16* WkvT  = (__bf16*)(scratch + 37748736);           //  2.1 MB
    __bf16* WqxT  = (__bf16*)(scratch + 39845888);           //  8.9 MB
    __bf16* KupxT = (__bf16*)(scratch + 48758784);           //  2.2 MB
    __bf16* WvupT = (__bf16*)(scratch + 50987008);           //  2.1 MB  (end 53.1 MB)
    // attention-phase aliases (overlay OK: all above dead by then)
    __bf16* opart  = (__bf16*)scratch;                       // 1280*32KB = 41.9 MB
    float*  mlpart = (float*)(scratch + (size_t)1280 * 128 * 128 * 2);  // 1.3 MB

    dim3 blk(256);

    // --- staging: converts + weight transposes (qr/kr folded in) ---
    f32_to_bf16<<<(ROWS * D + 255) / 256, blk, 0, stream>>>(x, xb, ROWS * D);
    transpose_conv<<<dim3(D / 64, DC / 64), blk, 0, stream>>>(Wkv, WkvT, D, DC);
    transpose_conv<<<dim3(D / 64, D / 64),  blk, 0, stream>>>(Wq, WqxT, D, D);
    transpose_conv<<<dim3(D / 64, 1),       blk, 0, stream>>>(Wqr, WqxT + (size_t)D * D, D, DR);
    transpose_conv<<<dim3(DC / 64, D / 64), blk, 0, stream>>>(Wkup, KupxT, DC, D);
    transpose_conv<<<dim3(DC / 64, 1),      blk, 0, stream>>>(Wkr, KupxT + (size_t)D * DC, DC, DR);
    transpose_conv<<<dim3(DC / 64, D / 64), blk, 0, stream>>>(Wvup, WvupT, DC, D);
    transpose_conv<<<dim3(D / 64, D / 64),  blk, 0, stream>>>(Wo, WoT, D, D);

    // --- ckv = x @ Wkv: fp32 -> entry cols 0..511 (ldc 576), bf16 -> ckvb ---
    gemm_bt<true, true><<<dim3(DC / 128, ROWS / 128), blk, 0, stream>>>(
        xb, WkvT, out1, ckvb, ROWS, D, 576, DC);

    // --- q_ext = x @ [Wq | Wqr] (N=2176), then rope qr cols ---
    gemm_bt<false, true><<<dim3(LDX / 128, ROWS / 128), blk, 0, stream>>>(
        xb, WqxT, (float*)nullptr, qext, ROWS, D, 0, LDX);
    rope_ext<<<(ROWS * 32 + 255) / 256, blk, 0, stream>>>(qext, (float*)nullptr);

    // --- k_ext = ckv @ [Wkup | Wkr] (N=2176), rope kr cols + entry 512..575 ---
    gemm_bt<false, true><<<dim3(LDX / 128, ROWS / 128), blk, 0, stream>>>(
        ckvb, KupxT, (float*)nullptr, kext, ROWS, DC, 0, LDX);
    rope_ext<<<(ROWS * 32 + 255) / 256, blk, 0, stream>>>(kext, out1);

    // --- v = ckv @ Wvup; transpose ---
    gemm_bt<false, true><<<dim3(D / 128, ROWS / 128), blk, 0, stream>>>(
        ckvb, WvupT, (float*)nullptr, vb, ROWS, DC, 0, D);
    transpose_v<<<dim3(Tt / 64, D / 64, Bb), blk, 0, stream>>>(vb, vtb);

    // --- attention: split-KV (q-tile 128) + reduce ---
    attn_split<<<dim3(4, Tt / 128, NH * Bb), blk, 0, stream>>>(
        qext, kext, vtb, opart, mlpart);
    attn_reduce<<<dim3(Tt / 128, NH * Bb), blk, 0, stream>>>(opart, mlpart, aob);

    // --- out0 = ao @ Wo ---
    gemm_bt<true, false><<<dim3(D / 128, ROWS / 128), blk, 0, stream>>>(
        aob, WoT, out0, (__bf16*)nullptr, ROWS, D, D, 0);
}

// Round 9
// 491.809 us; speedup vs baseline: 1.1270x; 1.1270x over previous
//
#include <hip/hip_runtime.h>
#include <math.h>
#include <type_traits>

#define D    2048
#define DC   512
#define DR   64
#define NH   16
#define HD   128
#define Bb   2
#define Tt   2048
#define ROWS (Bb*Tt)   // 4096
#define LDX  2176      // row stride of q_ext / k_ext (2048 + 64 + 64 pad)

typedef __bf16 bf16x8 __attribute__((ext_vector_type(8)));
typedef __bf16 bf16x4 __attribute__((ext_vector_type(4)));
typedef float  f32x4  __attribute__((ext_vector_type(4)));
typedef float  f32x16 __attribute__((ext_vector_type(16)));
typedef unsigned int uint;

typedef const void __attribute__((address_space(1))) gvoid;
typedef void       __attribute__((address_space(3))) lvoid;

__device__ __forceinline__ void load_lds16(const void* g, void* l) {
    __builtin_amdgcn_global_load_lds((gvoid*)g, (lvoid*)l, 16, 0, 0);
}

// ============ bf16 MFMA GEMM: C = A[M,K] @ BT[N,K]^T, ldc variants =========
// Natural blockIdx order (R4: XCD swizzling thrashes L2 on this dispatch).
template <bool WF32, bool WBF16>
__global__ __launch_bounds__(256)
void gemm_bt(const __bf16* __restrict__ A, const __bf16* __restrict__ BT,
             float* __restrict__ Cf, __bf16* __restrict__ Cb,
             int M, int K, int ldcf, int ldcb) {
    __shared__ __bf16 As[128 * 32];
    __shared__ __bf16 Bs[128 * 32];

    const int tid  = threadIdx.x;
    const int w    = tid >> 6;
    const int lane = tid & 63;
    const int quad = lane >> 4;
    const int lc   = lane & 15;
    const int bm   = blockIdx.y * 128;
    const int bn   = blockIdx.x * 128;
    const int wm   = (w & 1) * 64;
    const int wn   = (w >> 1) * 64;

    const int sr = w * 32 + (lane >> 2);
    const int sc = (lane & 3) * 8;

    f32x4 acc[4][4] = {};

    for (int k0 = 0; k0 < K; k0 += 32) {
        const __bf16* ga = A  + (size_t)(bm + sr) * K + k0 + sc;
        const __bf16* gb = BT + (size_t)(bn + sr) * K + k0 + sc;
        load_lds16(ga,                  &As[(w * 32) * 32]);
        load_lds16(ga + (size_t)16 * K, &As[(w * 32 + 16) * 32]);
        load_lds16(gb,                  &Bs[(w * 32) * 32]);
        load_lds16(gb + (size_t)16 * K, &Bs[(w * 32 + 16) * 32]);
        __syncthreads();

        bf16x8 af[4], bfr[4];
        #pragma unroll
        for (int mi = 0; mi < 4; ++mi)
            af[mi] = *(bf16x8*)&As[(wm + mi * 16 + lc) * 32 + quad * 8];
        #pragma unroll
        for (int ni = 0; ni < 4; ++ni)
            bfr[ni] = *(bf16x8*)&Bs[(wn + ni * 16 + lc) * 32 + quad * 8];
        #pragma unroll
        for (int mi = 0; mi < 4; ++mi)
            #pragma unroll
            for (int ni = 0; ni < 4; ++ni)
                acc[mi][ni] = __builtin_amdgcn_mfma_f32_16x16x32_bf16(
                    af[mi], bfr[ni], acc[mi][ni], 0, 0, 0);
        __syncthreads();
    }

    #pragma unroll
    for (int mi = 0; mi < 4; ++mi)
        #pragma unroll
        for (int r = 0; r < 4; ++r) {
            const int row = bm + wm + mi * 16 + quad * 4 + r;
            const int col = bn + wn + lc;
            #pragma unroll
            for (int ni = 0; ni < 4; ++ni) {
                float v = acc[mi][ni][r];
                if constexpr (WF32)  Cf[(size_t)row * ldcf + col + ni * 16] = v;
                if constexpr (WBF16) Cb[(size_t)row * ldcb + col + ni * 16] = (__bf16)v;
            }
        }
}

// ============ merged staging: x f32->bf16 (vectorized) + 7 transposes ======
// blocks [0,2048): x convert (float4, grid-stride)
// blocks [2048,4904): 64x64 transpose tiles, range-dispatched per weight
__global__ __launch_bounds__(256)
void stage_all(const float* __restrict__ x,
               const float* __restrict__ Wkv,  const float* __restrict__ Wq,
               const float* __restrict__ Wqr,  const float* __restrict__ Wkup,
               const float* __restrict__ Wkr,  const float* __restrict__ Wvup,
               const float* __restrict__ Wo,
               __bf16* __restrict__ xb,   __bf16* __restrict__ WkvT,
               __bf16* __restrict__ WqxT, __bf16* __restrict__ KupxT,
               __bf16* __restrict__ WvupT, __bf16* __restrict__ WoT) {
    __shared__ float tile[64][65];
    int bid = blockIdx.x;
    const int tid = threadIdx.x;

    if (bid < 2048) {
        const f32x4* in4 = (const f32x4*)x;
        const int n4 = ROWS * D / 4;          // 2,097,152
        for (int i = bid * 256 + tid; i < n4; i += 2048 * 256) {
            f32x4 v = in4[i];
            bf16x4 o;
            o[0] = (__bf16)v[0]; o[1] = (__bf16)v[1];
            o[2] = (__bf16)v[2]; o[3] = (__bf16)v[3];
            *(bf16x4*)(xb + (size_t)i * 4) = o;
        }
        return;
    }
    bid -= 2048;

    const float* W; __bf16* WT; int R, C, bx, by;
    if (bid < 256) {                                   // Wkv: (32 x 8)
        W = Wkv; WT = WkvT; R = D; C = DC; bx = bid & 31; by = bid >> 5;
    } else if (bid < 256 + 1024) {                     // Wq: (32 x 32)
        bid -= 256;
        W = Wq; WT = WqxT; R = D; C = D; bx = bid & 31; by = bid >> 5;
    } else if (bid < 256 + 1024 + 32) {                // Wqr: (32 x 1)
        bid -= 256 + 1024;
        W = Wqr; WT = WqxT + (size_t)D * D; R = D; C = DR; bx = bid; by = 0;
    } else if (bid < 256 + 1024 + 32 + 256) {          // Wkup: (8 x 32)
        bid -= 256 + 1024 + 32;
        W = Wkup; WT = KupxT; R = DC; C = D; bx = bid & 7; by = bid >> 3;
    } else if (bid < 256 + 1024 + 32 + 256 + 8) {      // Wkr: (8 x 1)
        bid -= 256 + 1024 + 32 + 256;
        W = Wkr; WT = KupxT + (size_t)D * DC; R = DC; C = DR; bx = bid; by = 0;
    } else if (bid < 256 + 1024 + 32 + 256 + 8 + 256) {// Wvup: (8 x 32)
        bid -= 256 + 1024 + 32 + 256 + 8;
        W = Wvup; WT = WvupT; R = DC; C = D; bx = bid & 7; by = bid >> 3;
    } else {                                           // Wo: (32 x 32)
        bid -= 256 + 1024 + 32 + 256 + 8 + 256;
        W = Wo; WT = WoT; R = D; C = D; bx = bid & 31; by = bid >> 5;
    }

    const int r0 = bx * 64;
    const int c0 = by * 64;
    for (int e = tid; e < 64 * 64; e += 256) {
        int i = e >> 6, j = e & 63;
        tile[i][j] = W[(size_t)(r0 + i) * C + c0 + j];
    }
    __syncthreads();
    for (int e = tid; e < 64 * 64; e += 256) {
        int i = e >> 6, j = e & 63;
        WT[(size_t)(c0 + i) * R + r0 + j] = (__bf16)tile[j][i];
    }
}

// ============ RoPE on BOTH ext-buffers in one launch =======================
// idx < ROWS*32: qext (no entry); else kext (+entry cols 512..575)
__global__ void rope2(__bf16* __restrict__ qp, __bf16* __restrict__ kp,
                      float* __restrict__ ent) {
    int idx = blockIdx.x * blockDim.x + threadIdx.x;
    if (idx >= 2 * ROWS * 32) return;
    const bool isk = idx >= ROWS * 32;
    if (isk) idx -= ROWS * 32;
    __bf16* p = isk ? kp : qp;
    int row = idx >> 5;
    int i   = idx & 31;
    int t   = row & (Tt - 1);
    float inv  = powf(10000.0f, -(float)(2 * i) / 64.0f);
    float fr   = (float)t * inv;
    float c = cosf(fr), s = sinf(fr);
    __bf16* v = p + (size_t)row * LDX + 2048;
    float x1 = (float)v[i], x2 = (float)v[i + 32];
    float o1 = x1 * c - x2 * s;
    float o2 = x2 * c + x1 * s;
    v[i]      = (__bf16)o1;
    v[i + 32] = (__bf16)o2;
    if (isk) {
        ent[(size_t)row * 576 + 512 + i] = o1;
        ent[(size_t)row * 576 + 544 + i] = o2;
    }
}

// ============ V transpose: vb[B][T][D] -> vtb[B][D][T] (bf16) ==============
__global__ __launch_bounds__(256)
void transpose_v(const __bf16* __restrict__ vb, __bf16* __restrict__ vtb) {
    __shared__ __bf16 tile[64][65];
    const int t0 = blockIdx.x * 64;
    const int c0 = blockIdx.y * 64;
    const int b  = blockIdx.z;
    const int tid = threadIdx.x;
    for (int e = tid; e < 64 * 64; e += 256) {
        int i = e >> 6, j = e & 63;
        tile[i][j] = vb[((size_t)(b * Tt + t0 + i)) * D + c0 + j];
    }
    __syncthreads();
    for (int e = tid; e < 64 * 64; e += 256) {
        int i = e >> 6, j = e & 63;
        vtb[((size_t)(b * D + c0 + i)) * Tt + t0 + j] = tile[j][i];
    }
}

// ============ split-KV MFMA flash attention (exact R3 best: 138 us) ========
// Q-tile = 128 queries (4 waves x 32 q each), KV tiles of 64 keys.
// S^T = K.Q^T via mfma_32x32x16 (lane owns ONE query: col = lane&31).
// P^T relayout acc->B-frag via wave-private LDS PsT. Always-rescale.
// LDS 62,464 B -> 2 blocks/CU (proven locality regime, R4/R5: 3 thrash L2).
// 1-deep register prefetch (R8: 2-deep spills past the 128-VGPR boundary).
#define KS_STR 200         // 192 cols + pad; 400B row
#define VT_STR 72          // 64 cols + pad; 144B row
#define PS_STR 72          // 64 cols + pad; 144B row (wave-private P^T)
#define SPLIT_TILES 8

// packed partial-slot base for q-tile qt (ntiles = 2qt+2, splits of 8)
__device__ __forceinline__ int pbase_qt(int qt) {
    int a = qt >> 2, r = qt & 3;
    return qt + 2 * a * (a - 1) + r * a;
}

__global__ __launch_bounds__(256, 2)
void attn_split(const __bf16* __restrict__ qx, const __bf16* __restrict__ kx,
                const __bf16* __restrict__ vtb, __bf16* __restrict__ opart,
                float* __restrict__ mlpart) {
    const int qt = (Tt / 128 - 1) - (int)blockIdx.y;   // longest-first
    const int sp = blockIdx.x;
    const int t0 = sp * SPLIT_TILES;
    const int ntiles = 2 * qt + 2;
    if (t0 >= ntiles) return;                           // unused split slot
    const int tend = min(t0 + SPLIT_TILES, ntiles);
    const int hb = blockIdx.z;
    const int h  = hb & (NH - 1);
    const int b  = hb >> 4;
    const int q0 = qt * 128;

    __shared__ __bf16 Ks[64][KS_STR];     // 25.6 KB (k cols 0..127, kr 128..191)
    __shared__ __bf16 Vt[128][VT_STR];    // 18.4 KB
    __shared__ __bf16 PsT[4][32][PS_STR]; // 18.4 KB wave-private P^T[q][key]

    const int tid    = threadIdx.x;
    const int w      = tid >> 6;
    const int lane   = tid & 63;
    const int lane31 = lane & 31;
    const int hi     = lane >> 5;
    const int hi8    = hi * 8;
    const int hi4    = hi * 4;

    // per-wave last tile actually needed (later tiles fully masked -> skip compute)
    const int qwmax = q0 + w * 32 + 31;
    const int tendw = min(tend, (qwmax >> 6) + 1);
    const int qglob = q0 + w * 32 + lane31;             // this lane's query

    // ---- Q fragments (B-operand: col = q = lane&31, k = hi*8+e per slice) ----
    bf16x8 aq[12];
    {
        const __bf16* qrow = qx + (size_t)(b * Tt + q0 + w * 32 + lane31) * LDX;
        #pragma unroll
        for (int kt = 0; kt < 8; ++kt)
            aq[kt] = *(const bf16x8*)(qrow + h * HD + kt * 16 + hi8);
        #pragma unroll
        for (int kt = 0; kt < 4; ++kt)
            aq[8 + kt] = *(const bf16x8*)(qrow + 2048 + kt * 16 + hi8);
    }

    // ---- staging geometry (K tile 64x192, V tile 128x64) ----
    int krow[6], kcol[6], kgo[6];
    #pragma unroll
    for (int j = 0; j < 6; ++j) {
        int c   = tid + j * 256;
        int row = c / 24, c24 = c - row * 24;
        krow[j] = row;
        kcol[j] = c24 * 8;
        kgo[j]  = row * LDX + ((c24 < 16) ? (h * HD + c24 * 8)
                                          : (2048 + (c24 - 16) * 8));
    }
    const int vrow = tid >> 3;
    const int vcol = (tid & 7) * 8;
    const __bf16* kb0 = kx + (size_t)b * Tt * LDX;
    const __bf16* vb0 = vtb + ((size_t)b * D + (size_t)h * HD) * Tt;

    bf16x8 pk[6], pvv[4];
    {
        const __bf16* kbt = kb0 + (size_t)(t0 * 64) * LDX;
        const __bf16* vbt = vb0 + t0 * 64;
        #pragma unroll
        for (int j = 0; j < 6; ++j) pk[j] = *(const bf16x8*)(kbt + kgo[j]);
        #pragma unroll
        for (int j = 0; j < 4; ++j)
            pvv[j] = *(const bf16x8*)(vbt + (vrow + j * 32) * Tt + vcol);
    }

    float m_i = -1e30f, l_i = 0.f;      // per-lane: ONE query (lane&31)
    f32x16 Of[4] = {};                   // O^T: hd = nb*32 + crow(r,hi), q = lane&31

    const float rscale = 0.07216878364870323f;   // 1/sqrt(192)

    for (int it = t0; it < tend; ++it) {
        const int s0 = it * 64;
        __syncthreads();
        #pragma unroll
        for (int j = 0; j < 6; ++j) *(bf16x8*)&Ks[krow[j]][kcol[j]] = pk[j];
        #pragma unroll
        for (int j = 0; j < 4; ++j) *(bf16x8*)&Vt[vrow + j * 32][vcol] = pvv[j];
        __syncthreads();

        if (it + 1 < tend) {                      // T14: loads in flight over compute
            const __bf16* kbn = kb0 + (size_t)(s0 + 64) * LDX;
            const __bf16* vbn = vb0 + (s0 + 64);
            #pragma unroll
            for (int j = 0; j < 6; ++j) pk[j] = *(const bf16x8*)(kbn + kgo[j]);
            #pragma unroll
            for (int j = 0; j < 4; ++j)
                pvv[j] = *(const bf16x8*)(vbn + (vrow + j * 32) * Tt + vcol);
        }

        if (it < tendw) {
            // ---- S^T = K Q^T : st0/st1 cover keys {0..31},{32..63} ----
            f32x16 st0 = {}, st1 = {};
            __builtin_amdgcn_s_setprio(1);
            #pragma unroll
            for (int kt = 0; kt < 12; ++kt) {
                bf16x8 ak0 = *(bf16x8*)&Ks[lane31][kt * 16 + hi8];
                bf16x8 ak1 = *(bf16x8*)&Ks[32 + lane31][kt * 16 + hi8];
                st0 = __builtin_amdgcn_mfma_f32_32x32x16_bf16(ak0, aq[kt], st0, 0, 0, 0);
                st1 = __builtin_amdgcn_mfma_f32_32x32x16_bf16(ak1, aq[kt], st1, 0, 0, 0);
            }
            __builtin_amdgcn_s_setprio(0);

            // ---- scalarize + mask + tile max (key = ksub*32 + (r&3)+8*(r>>2)+4*hi) ----
            const bool dm = (s0 + 63 > q0 + w * 32);
            float sv0[16], sv1[16];
            float mt = -1e30f;
            #pragma unroll
            for (int r = 0; r < 16; ++r) {
                float a0 = st0[r] * rscale;
                float a1 = st1[r] * rscale;
                if (dm) {
                    int kr = (r & 3) + 8 * (r >> 2) + hi4;
                    if (s0 + kr > qglob)      a0 = -1e30f;
                    if (s0 + 32 + kr > qglob) a1 = -1e30f;
                }
                sv0[r] = a0; sv1[r] = a1;
                mt = fmaxf(mt, fmaxf(a0, a1));
            }
            mt = fmaxf(mt, __shfl_xor(mt, 32, 64));

            // ---- always-rescale online softmax ----
            float mn = fmaxf(m_i, mt);
            float al = __expf(m_i - mn);
            m_i = mn;

            // ---- P^T -> wave-private LDS ----
            float rsum = 0.f;
            #pragma unroll
            for (int g = 0; g < 4; ++g) {
                bf16x4 pr;
                #pragma unroll
                for (int j = 0; j < 4; ++j) {
                    __bf16 pb = (__bf16)__expf(sv0[g * 4 + j] - mn);
                    pr[j] = pb;
                    rsum += (float)pb;
                }
                *(bf16x4*)&PsT[w][lane31][g * 8 + hi4] = pr;
            }
            #pragma unroll
            for (int g = 0; g < 4; ++g) {
                bf16x4 pr;
                #pragma unroll
                for (int j = 0; j < 4; ++j) {
                    __bf16 pb = (__bf16)__expf(sv1[g * 4 + j] - mn);
                    pr[j] = pb;
                    rsum += (float)pb;
                }
                *(bf16x4*)&PsT[w][lane31][32 + g * 8 + hi4] = pr;
            }
            rsum += __shfl_xor(rsum, 32, 64);
            l_i = l_i * al + rsum;
            #pragma unroll
            for (int nb = 0; nb < 4; ++nb) Of[nb] *= al;

            // ---- O^T += Vt P^T (A = Vt rows = hd, B = P^T cols = q) ----
            __builtin_amdgcn_s_setprio(1);
            #pragma unroll
            for (int kblk = 0; kblk < 4; ++kblk) {
                bf16x8 bp = *(bf16x8*)&PsT[w][lane31][kblk * 16 + hi8];
                #pragma unroll
                for (int nb = 0; nb < 4; ++nb) {
                    bf16x8 av = *(bf16x8*)&Vt[nb * 32 + lane31][kblk * 16 + hi8];
                    Of[nb] = __builtin_amdgcn_mfma_f32_32x32x16_bf16(av, bp, Of[nb], 0, 0, 0);
                }
            }
            __builtin_amdgcn_s_setprio(0);
        }
    }

    // ---- write partials: O row q = w*32+lane31, cols hd = nb*32 + g*8 + hi*4 + j ----
    const int p = hb * 40 + pbase_qt(qt) + sp;
    __bf16* ob = opart + (size_t)p * (128 * 128) + (size_t)(w * 32 + lane31) * 128;
    #pragma unroll
    for (int nb = 0; nb < 4; ++nb)
        #pragma unroll
        for (int g = 0; g < 4; ++g) {
            bf16x4 o4;
            #pragma unroll
            for (int j = 0; j < 4; ++j) o4[j] = (__bf16)Of[nb][g * 4 + j];
            *(bf16x4*)(ob + nb * 32 + g * 8 + hi4) = o4;
        }
    if (hi == 0) {
        mlpart[(size_t)p * 256 + w * 32 + lane31]       = m_i;
        mlpart[(size_t)p * 256 + 128 + w * 32 + lane31] = l_i;
    }
}

// ============ combine split partials -> aob (bf16) =========================
__global__ __launch_bounds__(256)
void attn_reduce(const __bf16* __restrict__ opart, const float* __restrict__ mlpart,
                 __bf16* __restrict__ aob) {
    const int qt = blockIdx.x;                // 0..15 (q-tiles of 128)
    const int hb = blockIdx.y;
    const int h  = hb & (NH - 1);
    const int b  = hb >> 4;
    const int nsp = (qt >> 2) + 1;
    const int p0  = hb * 40 + pbase_qt(qt);
    const int tid = threadIdx.x;
    const int ql  = tid >> 1;                 // 0..127
    const int cg  = (tid & 1) * 64;

    float M = -1e30f;
    for (int s = 0; s < nsp; ++s)
        M = fmaxf(M, mlpart[(size_t)(p0 + s) * 256 + ql]);
    float L = 0.f;
    float acc[64];
    #pragma unroll
    for (int j = 0; j < 64; ++j) acc[j] = 0.f;
    for (int s = 0; s < nsp; ++s) {
        float ms = mlpart[(size_t)(p0 + s) * 256 + ql];
        float ls = mlpart[(size_t)(p0 + s) * 256 + 128 + ql];
        float sc = __expf(ms - M);
        L += ls * sc;
        const __bf16* op = opart + (size_t)(p0 + s) * (128 * 128) + (size_t)ql * 128 + cg;
        #pragma unroll
        for (int j8 = 0; j8 < 4; ++j8) {
            bf16x8 v = *(const bf16x8*)(op + j8 * 8);
            #pragma unroll
            for (int e = 0; e < 8; ++e) acc[j8 * 8 + e] += sc * (float)v[e];
        }
        const __bf16* op2 = op + 32;
        #pragma unroll
        for (int j8 = 0; j8 < 4; ++j8) {
            bf16x8 v = *(const bf16x8*)(op2 + j8 * 8);
            #pragma unroll
            for (int e = 0; e < 8; ++e) acc[32 + j8 * 8 + e] += sc * (float)v[e];
        }
    }
    float invL = 1.0f / L;
    __bf16* outp = aob + ((size_t)(b * Tt + qt * 128 + ql)) * D + h * HD + cg;
    #pragma unroll
    for (int j8 = 0; j8 < 8; ++j8) {
        bf16x8 v;
        #pragma unroll
        for (int e = 0; e < 8; ++e) v[e] = (__bf16)(acc[j8 * 8 + e] * invL);
        *(bf16x8*)(outp + j8 * 8) = v;
    }
}

extern "C" void kernel_launch(void* const* d_in, const int* in_sizes, int n_in,
                              void* d_out, int out_size, void* d_ws, size_t ws_size,
                              hipStream_t stream) {
    const float* x    = (const float*)d_in[0];
    const float* Wkv  = (const float*)d_in[1];
    const float* Wkup = (const float*)d_in[2];
    const float* Wvup = (const float*)d_in[3];
    const float* Wq   = (const float*)d_in[4];
    const float* Wqr  = (const float*)d_in[5];
    const float* Wkr  = (const float*)d_in[6];
    const float* Wo   = (const float*)d_in[7];

    float* out0 = (float*)d_out;                     // (4096, 2048)
    float* out1 = out0 + (size_t)ROWS * D;           // (4096, 576) entry

    // ---- persistent buffers ----
    char* wsb = (char*)d_ws;
    __bf16* qext = (__bf16*)wsb;  wsb += (size_t)ROWS * LDX * 2;   // 17.8 MB
    __bf16* kext = (__bf16*)wsb;  wsb += (size_t)ROWS * LDX * 2;   // 17.8 MB
    __bf16* vtb  = (__bf16*)wsb;  wsb += (size_t)ROWS * D   * 2;   // 16.8 MB
    __bf16* aob  = (__bf16*)wsb;  wsb += (size_t)ROWS * D   * 2;   // 16.8 MB
    __bf16* WoT  = (__bf16*)wsb;  wsb += (size_t)D * D * 2;        //  8.4 MB

    // ---- phase-1 scratch (dead before attention) / attention partials ----
    char* scratch = wsb;
    __bf16* xb    = (__bf16*)scratch;                        // 16.8 MB
    __bf16* vb    = (__bf16*)(scratch + 16777216);           // 16.8 MB
    __bf16* ckvb  = (__bf16*)(scratch + 33554432);           //  4.2 MB
    __bf16* WkvT  = (__bf16*)(scratch + 37748736);           //  2.1 MB
    __bf16* WqxT  = (__bf16*)(scratch + 39845888);           //  8.9 MB
    __bf16* KupxT = (__bf16*)(scratch + 48758784);           //  2.2 MB
    __bf16* WvupT = (__bf16*)(scratch + 50987008);           //  2.1 MB  (end 53.1 MB)
    // attention-phase aliases (overlay OK: all above dead by then)
    __bf16* opart  = (__bf16*)scratch;                       // 1280*32KB = 41.9 MB
    float*  mlpart = (float*)(scratch + (size_t)1280 * 128 * 128 * 2);  // 1.3 MB

    dim3 blk(256);

    // --- merged staging: x convert + all weight transposes (1 launch) ---
    stage_all<<<dim3(2048 + 2856), blk, 0, stream>>>(
        x, Wkv, Wq, Wqr, Wkup, Wkr, Wvup, Wo,
        xb, WkvT, WqxT, KupxT, WvupT, WoT);

    // --- ckv = x @ Wkv: fp32 -> entry cols 0..511 (ldc 576), bf16 -> ckvb ---
    gemm_bt<true, true><<<dim3(DC / 128, ROWS / 128), blk, 0, stream>>>(
        xb, WkvT, out1, ckvb, ROWS, D, 576, DC);

    // --- q_ext = x @ [Wq | Wqr] (N=2176) ---
    gemm_bt<false, true><<<dim3(LDX / 128, ROWS / 128), blk, 0, stream>>>(
        xb, WqxT, (float*)nullptr, qext, ROWS, D, 0, LDX);

    // --- k_ext = ckv @ [Wkup | Wkr] (N=2176) ---
    gemm_bt<false, true><<<dim3(LDX / 128, ROWS / 128), blk, 0, stream>>>(
        ckvb, KupxT, (float*)nullptr, kext, ROWS, DC, 0, LDX);

    // --- rope both ext buffers (merged; kext half also fills entry cols) ---
    rope2<<<(2 * ROWS * 32 + 255) / 256, blk, 0, stream>>>(qext, kext, out1);

    // --- v = ckv @ Wvup; transpose ---
    gemm_bt<false, true><<<dim3(D / 128, ROWS / 128), blk, 0, stream>>>(
        ckvb, WvupT, (float*)nullptr, vb, ROWS, DC, 0, D);
    transpose_v<<<dim3(Tt / 64, D / 64, Bb), blk, 0, stream>>>(vb, vtb);

    // --- attention: split-KV (q-tile 128) + reduce ---
    attn_split<<<dim3(4, Tt / 128, NH * Bb), blk, 0, stream>>>(
        qext, kext, vtb, opart, mlpart);
    attn_reduce<<<dim3(Tt / 128, NH * Bb), blk, 0, stream>>>(opart, mlpart, aob);

    // --- out0 = ao @ Wo ---
    gemm_bt<true, false><<<dim3(D / 128, ROWS / 128), blk, 0, stream>>>(
        aob, WoT, out0, (__bf16*)nullptr, ROWS, D, D, 0);
}

// Round 10
// 443.716 us; speedup vs baseline: 1.2492x; 1.1084x over previous
//
#include <hip/hip_runtime.h>
#include <math.h>
#include <type_traits>

#define D    2048
#define DC   512
#define DR   64
#define NH   16
#define HD   128
#define Bb   2
#define Tt   2048
#define ROWS (Bb*Tt)   // 4096
#define LDX  2176      // row stride of q_ext / k_ext (2048 + 64 + 64 pad)

typedef __bf16 bf16x8 __attribute__((ext_vector_type(8)));
typedef __bf16 bf16x4 __attribute__((ext_vector_type(4)));
typedef float  f32x4  __attribute__((ext_vector_type(4)));
typedef float  f32x16 __attribute__((ext_vector_type(16)));
typedef unsigned int uint;

typedef const void __attribute__((address_space(1))) gvoid;
typedef void       __attribute__((address_space(3))) lvoid;

__device__ __forceinline__ void load_lds16(const void* g, void* l) {
    __builtin_amdgcn_global_load_lds((gvoid*)g, (lvoid*)l, 16, 0, 0);
}

// ============ bf16 MFMA GEMM: C = A[M,K] @ BT[N,K]^T, ldc variants =========
// Natural blockIdx order (R4: XCD swizzling thrashes L2 on this dispatch).
template <bool WF32, bool WBF16>
__global__ __launch_bounds__(256)
void gemm_bt(const __bf16* __restrict__ A, const __bf16* __restrict__ BT,
             float* __restrict__ Cf, __bf16* __restrict__ Cb,
             int M, int K, int ldcf, int ldcb) {
    __shared__ __bf16 As[128 * 32];
    __shared__ __bf16 Bs[128 * 32];

    const int tid  = threadIdx.x;
    const int w    = tid >> 6;
    const int lane = tid & 63;
    const int quad = lane >> 4;
    const int lc   = lane & 15;
    const int bm   = blockIdx.y * 128;
    const int bn   = blockIdx.x * 128;
    const int wm   = (w & 1) * 64;
    const int wn   = (w >> 1) * 64;

    const int sr = w * 32 + (lane >> 2);
    const int sc = (lane & 3) * 8;

    f32x4 acc[4][4] = {};

    for (int k0 = 0; k0 < K; k0 += 32) {
        const __bf16* ga = A  + (size_t)(bm + sr) * K + k0 + sc;
        const __bf16* gb = BT + (size_t)(bn + sr) * K + k0 + sc;
        load_lds16(ga,                  &As[(w * 32) * 32]);
        load_lds16(ga + (size_t)16 * K, &As[(w * 32 + 16) * 32]);
        load_lds16(gb,                  &Bs[(w * 32) * 32]);
        load_lds16(gb + (size_t)16 * K, &Bs[(w * 32 + 16) * 32]);
        __syncthreads();

        bf16x8 af[4], bfr[4];
        #pragma unroll
        for (int mi = 0; mi < 4; ++mi)
            af[mi] = *(bf16x8*)&As[(wm + mi * 16 + lc) * 32 + quad * 8];
        #pragma unroll
        for (int ni = 0; ni < 4; ++ni)
            bfr[ni] = *(bf16x8*)&Bs[(wn + ni * 16 + lc) * 32 + quad * 8];
        #pragma unroll
        for (int mi = 0; mi < 4; ++mi)
            #pragma unroll
            for (int ni = 0; ni < 4; ++ni)
                acc[mi][ni] = __builtin_amdgcn_mfma_f32_16x16x32_bf16(
                    af[mi], bfr[ni], acc[mi][ni], 0, 0, 0);
        __syncthreads();
    }

    #pragma unroll
    for (int mi = 0; mi < 4; ++mi)
        #pragma unroll
        for (int r = 0; r < 4; ++r) {
            const int row = bm + wm + mi * 16 + quad * 4 + r;
            const int col = bn + wn + lc;
            #pragma unroll
            for (int ni = 0; ni < 4; ++ni) {
                float v = acc[mi][ni][r];
                if constexpr (WF32)  Cf[(size_t)row * ldcf + col + ni * 16] = v;
                if constexpr (WBF16) Cb[(size_t)row * ldcb + col + ni * 16] = (__bf16)v;
            }
        }
}

// ============ column-split GEMM: one A, concatenated BT, two C regions =====
// bn < nsplit: region 1 -> (optional f32 Cf1 ldcf1) + bf16 Cb1 ldcb1, col=bn..
// bn >= nsplit: region 2 -> bf16 Cb2 ldcb2, col = bn-nsplit..
// Identical staging/MFMA to gemm_bt; only epilogue targets differ (uniform
// per block since nsplit % 128 == 0).
template <bool R1F32>
__global__ __launch_bounds__(256)
void gemm_split(const __bf16* __restrict__ A, const __bf16* __restrict__ BT,
                float* __restrict__ Cf1, __bf16* __restrict__ Cb1,
                __bf16* __restrict__ Cb2,
                int ldcf1, int ldcb1, int ldcb2, int nsplit,
                int M, int K) {
    __shared__ __bf16 As[128 * 32];
    __shared__ __bf16 Bs[128 * 32];

    const int tid  = threadIdx.x;
    const int w    = tid >> 6;
    const int lane = tid & 63;
    const int quad = lane >> 4;
    const int lc   = lane & 15;
    const int bm   = blockIdx.y * 128;
    const int bn   = blockIdx.x * 128;
    const int wm   = (w & 1) * 64;
    const int wn   = (w >> 1) * 64;

    const int sr = w * 32 + (lane >> 2);
    const int sc = (lane & 3) * 8;

    f32x4 acc[4][4] = {};

    for (int k0 = 0; k0 < K; k0 += 32) {
        const __bf16* ga = A  + (size_t)(bm + sr) * K + k0 + sc;
        const __bf16* gb = BT + (size_t)(bn + sr) * K + k0 + sc;
        load_lds16(ga,                  &As[(w * 32) * 32]);
        load_lds16(ga + (size_t)16 * K, &As[(w * 32 + 16) * 32]);
        load_lds16(gb,                  &Bs[(w * 32) * 32]);
        load_lds16(gb + (size_t)16 * K, &Bs[(w * 32 + 16) * 32]);
        __syncthreads();

        bf16x8 af[4], bfr[4];
        #pragma unroll
        for (int mi = 0; mi < 4; ++mi)
            af[mi] = *(bf16x8*)&As[(wm + mi * 16 + lc) * 32 + quad * 8];
        #pragma unroll
        for (int ni = 0; ni < 4; ++ni)
            bfr[ni] = *(bf16x8*)&Bs[(wn + ni * 16 + lc) * 32 + quad * 8];
        #pragma unroll
        for (int mi = 0; mi < 4; ++mi)
            #pragma unroll
            for (int ni = 0; ni < 4; ++ni)
                acc[mi][ni] = __builtin_amdgcn_mfma_f32_16x16x32_bf16(
                    af[mi], bfr[ni], acc[mi][ni], 0, 0, 0);
        __syncthreads();
    }

    const bool r1 = (bn < nsplit);
    #pragma unroll
    for (int mi = 0; mi < 4; ++mi)
        #pragma unroll
        for (int r = 0; r < 4; ++r) {
            const int row = bm + wm + mi * 16 + quad * 4 + r;
            const int col = bn + wn + lc;
            #pragma unroll
            for (int ni = 0; ni < 4; ++ni) {
                float v = acc[mi][ni][r];
                if (r1) {
                    if constexpr (R1F32)
                        Cf1[(size_t)row * ldcf1 + col + ni * 16] = v;
                    Cb1[(size_t)row * ldcb1 + col + ni * 16] = (__bf16)v;
                } else {
                    Cb2[(size_t)row * ldcb2 + (col - nsplit) + ni * 16] = (__bf16)v;
                }
            }
        }
}

// ============ merged staging: x f32->bf16 (vectorized) + 7 transposes ======
// blocks [0,2048): x convert (float4, grid-stride)
// blocks [2048,4904): 64x64 transpose tiles, range-dispatched per weight
__global__ __launch_bounds__(256)
void stage_all(const float* __restrict__ x,
               const float* __restrict__ Wkv,  const float* __restrict__ Wq,
               const float* __restrict__ Wqr,  const float* __restrict__ Wkup,
               const float* __restrict__ Wkr,  const float* __restrict__ Wvup,
               const float* __restrict__ Wo,
               __bf16* __restrict__ xb,   __bf16* __restrict__ WkvT,
               __bf16* __restrict__ WqxT, __bf16* __restrict__ KupxT,
               __bf16* __restrict__ WvupT, __bf16* __restrict__ WoT) {
    __shared__ float tile[64][65];
    int bid = blockIdx.x;
    const int tid = threadIdx.x;

    if (bid < 2048) {
        const f32x4* in4 = (const f32x4*)x;
        const int n4 = ROWS * D / 4;          // 2,097,152
        for (int i = bid * 256 + tid; i < n4; i += 2048 * 256) {
            f32x4 v = in4[i];
            bf16x4 o;
            o[0] = (__bf16)v[0]; o[1] = (__bf16)v[1];
            o[2] = (__bf16)v[2]; o[3] = (__bf16)v[3];
            *(bf16x4*)(xb + (size_t)i * 4) = o;
        }
        return;
    }
    bid -= 2048;

    const float* W; __bf16* WT; int R, C, bx, by;
    if (bid < 256) {                                   // Wkv: (32 x 8)
        W = Wkv; WT = WkvT; R = D; C = DC; bx = bid & 31; by = bid >> 5;
    } else if (bid < 256 + 1024) {                     // Wq: (32 x 32)
        bid -= 256;
        W = Wq; WT = WqxT; R = D; C = D; bx = bid & 31; by = bid >> 5;
    } else if (bid < 256 + 1024 + 32) {                // Wqr: (32 x 1)
        bid -= 256 + 1024;
        W = Wqr; WT = WqxT + (size_t)D * D; R = D; C = DR; bx = bid; by = 0;
    } else if (bid < 256 + 1024 + 32 + 256) {          // Wkup: (8 x 32)
        bid -= 256 + 1024 + 32;
        W = Wkup; WT = KupxT; R = DC; C = D; bx = bid & 7; by = bid >> 3;
    } else if (bid < 256 + 1024 + 32 + 256 + 8) {      // Wkr: (8 x 1)
        bid -= 256 + 1024 + 32 + 256;
        W = Wkr; WT = KupxT + (size_t)D * DC; R = DC; C = DR; bx = bid; by = 0;
    } else if (bid < 256 + 1024 + 32 + 256 + 8 + 256) {// Wvup: (8 x 32)
        bid -= 256 + 1024 + 32 + 256 + 8;
        W = Wvup; WT = WvupT; R = DC; C = D; bx = bid & 7; by = bid >> 3;
    } else {                                           // Wo: (32 x 32)
        bid -= 256 + 1024 + 32 + 256 + 8 + 256;
        W = Wo; WT = WoT; R = D; C = D; bx = bid & 31; by = bid >> 5;
    }

    const int r0 = bx * 64;
    const int c0 = by * 64;
    for (int e = tid; e < 64 * 64; e += 256) {
        int i = e >> 6, j = e & 63;
        tile[i][j] = W[(size_t)(r0 + i) * C + c0 + j];
    }
    __syncthreads();
    for (int e = tid; e < 64 * 64; e += 256) {
        int i = e >> 6, j = e & 63;
        WT[(size_t)(c0 + i) * R + r0 + j] = (__bf16)tile[j][i];
    }
}

// ============ RoPE on BOTH ext-buffers in one launch =======================
// idx < ROWS*32: qext (no entry); else kext (+entry cols 512..575)
__global__ void rope2(__bf16* __restrict__ qp, __bf16* __restrict__ kp,
                      float* __restrict__ ent) {
    int idx = blockIdx.x * blockDim.x + threadIdx.x;
    if (idx >= 2 * ROWS * 32) return;
    const bool isk = idx >= ROWS * 32;
    if (isk) idx -= ROWS * 32;
    __bf16* p = isk ? kp : qp;
    int row = idx >> 5;
    int i   = idx & 31;
    int t   = row & (Tt - 1);
    float inv  = powf(10000.0f, -(float)(2 * i) / 64.0f);
    float fr   = (float)t * inv;
    float c = cosf(fr), s = sinf(fr);
    __bf16* v = p + (size_t)row * LDX + 2048;
    float x1 = (float)v[i], x2 = (float)v[i + 32];
    float o1 = x1 * c - x2 * s;
    float o2 = x2 * c + x1 * s;
    v[i]      = (__bf16)o1;
    v[i + 32] = (__bf16)o2;
    if (isk) {
        ent[(size_t)row * 576 + 512 + i] = o1;
        ent[(size_t)row * 576 + 544 + i] = o2;
    }
}

// ============ V transpose: vb[B][T][D] -> vtb[B][D][T] (bf16) ==============
__global__ __launch_bounds__(256)
void transpose_v(const __bf16* __restrict__ vb, __bf16* __restrict__ vtb) {
    __shared__ __bf16 tile[64][65];
    const int t0 = blockIdx.x * 64;
    const int c0 = blockIdx.y * 64;
    const int b  = blockIdx.z;
    const int tid = threadIdx.x;
    for (int e = tid; e < 64 * 64; e += 256) {
        int i = e >> 6, j = e & 63;
        tile[i][j] = vb[((size_t)(b * Tt + t0 + i)) * D + c0 + j];
    }
    __syncthreads();
    for (int e = tid; e < 64 * 64; e += 256) {
        int i = e >> 6, j = e & 63;
        vtb[((size_t)(b * D + c0 + i)) * Tt + t0 + j] = tile[j][i];
    }
}

// ============ split-KV MFMA flash attention (exact R3 best: 138 us) ========
// Q-tile = 128 queries (4 waves x 32 q each), KV tiles of 64 keys.
// S^T = K.Q^T via mfma_32x32x16 (lane owns ONE query: col = lane&31).
// P^T relayout acc->B-frag via wave-private LDS PsT. Always-rescale.
// LDS 62,464 B -> 2 blocks/CU (proven locality regime, R4/R5: 3 thrash L2).
// 1-deep register prefetch (R8: 2-deep spills past the 128-VGPR boundary).
#define KS_STR 200         // 192 cols + pad; 400B row
#define VT_STR 72          // 64 cols + pad; 144B row
#define PS_STR 72          // 64 cols + pad; 144B row (wave-private P^T)
#define SPLIT_TILES 8

// packed partial-slot base for q-tile qt (ntiles = 2qt+2, splits of 8)
__device__ __forceinline__ int pbase_qt(int qt) {
    int a = qt >> 2, r = qt & 3;
    return qt + 2 * a * (a - 1) + r * a;
}

__global__ __launch_bounds__(256, 2)
void attn_split(const __bf16* __restrict__ qx, const __bf16* __restrict__ kx,
                const __bf16* __restrict__ vtb, __bf16* __restrict__ opart,
                float* __restrict__ mlpart) {
    const int qt = (Tt / 128 - 1) - (int)blockIdx.y;   // longest-first
    const int sp = blockIdx.x;
    const int t0 = sp * SPLIT_TILES;
    const int ntiles = 2 * qt + 2;
    if (t0 >= ntiles) return;                           // unused split slot
    const int tend = min(t0 + SPLIT_TILES, ntiles);
    const int hb = blockIdx.z;
    const int h  = hb & (NH - 1);
    const int b  = hb >> 4;
    const int q0 = qt * 128;

    __shared__ __bf16 Ks[64][KS_STR];     // 25.6 KB (k cols 0..127, kr 128..191)
    __shared__ __bf16 Vt[128][VT_STR];    // 18.4 KB
    __shared__ __bf16 PsT[4][32][PS_STR]; // 18.4 KB wave-private P^T[q][key]

    const int tid    = threadIdx.x;
    const int w      = tid >> 6;
    const int lane   = tid & 63;
    const int lane31 = lane & 31;
    const int hi     = lane >> 5;
    const int hi8    = hi * 8;
    const int hi4    = hi * 4;

    // per-wave last tile actually needed (later tiles fully masked -> skip compute)
    const int qwmax = q0 + w * 32 + 31;
    const int tendw = min(tend, (qwmax >> 6) + 1);
    const int qglob = q0 + w * 32 + lane31;             // this lane's query

    // ---- Q fragments (B-operand: col = q = lane&31, k = hi*8+e per slice) ----
    bf16x8 aq[12];
    {
        const __bf16* qrow = qx + (size_t)(b * Tt + q0 + w * 32 + lane31) * LDX;
        #pragma unroll
        for (int kt = 0; kt < 8; ++kt)
            aq[kt] = *(const bf16x8*)(qrow + h * HD + kt * 16 + hi8);
        #pragma unroll
        for (int kt = 0; kt < 4; ++kt)
            aq[8 + kt] = *(const bf16x8*)(qrow + 2048 + kt * 16 + hi8);
    }

    // ---- staging geometry (K tile 64x192, V tile 128x64) ----
    int krow[6], kcol[6], kgo[6];
    #pragma unroll
    for (int j = 0; j < 6; ++j) {
        int c   = tid + j * 256;
        int row = c / 24, c24 = c - row * 24;
        krow[j] = row;
        kcol[j] = c24 * 8;
        kgo[j]  = row * LDX + ((c24 < 16) ? (h * HD + c24 * 8)
                                          : (2048 + (c24 - 16) * 8));
    }
    const int vrow = tid >> 3;
    const int vcol = (tid & 7) * 8;
    const __bf16* kb0 = kx + (size_t)b * Tt * LDX;
    const __bf16* vb0 = vtb + ((size_t)b * D + (size_t)h * HD) * Tt;

    bf16x8 pk[6], pvv[4];
    {
        const __bf16* kbt = kb0 + (size_t)(t0 * 64) * LDX;
        const __bf16* vbt = vb0 + t0 * 64;
        #pragma unroll
        for (int j = 0; j < 6; ++j) pk[j] = *(const bf16x8*)(kbt + kgo[j]);
        #pragma unroll
        for (int j = 0; j < 4; ++j)
            pvv[j] = *(const bf16x8*)(vbt + (vrow + j * 32) * Tt + vcol);
    }

    float m_i = -1e30f, l_i = 0.f;      // per-lane: ONE query (lane&31)
    f32x16 Of[4] = {};                   // O^T: hd = nb*32 + crow(r,hi), q = lane&31

    const float rscale = 0.07216878364870323f;   // 1/sqrt(192)

    for (int it = t0; it < tend; ++it) {
        const int s0 = it * 64;
        __syncthreads();
        #pragma unroll
        for (int j = 0; j < 6; ++j) *(bf16x8*)&Ks[krow[j]][kcol[j]] = pk[j];
        #pragma unroll
        for (int j = 0; j < 4; ++j) *(bf16x8*)&Vt[vrow + j * 32][vcol] = pvv[j];
        __syncthreads();

        if (it + 1 < tend) {                      // T14: loads in flight over compute
            const __bf16* kbn = kb0 + (size_t)(s0 + 64) * LDX;
            const __bf16* vbn = vb0 + (s0 + 64);
            #pragma unroll
            for (int j = 0; j < 6; ++j) pk[j] = *(const bf16x8*)(kbn + kgo[j]);
            #pragma unroll
            for (int j = 0; j < 4; ++j)
                pvv[j] = *(const bf16x8*)(vbn + (vrow + j * 32) * Tt + vcol);
        }

        if (it < tendw) {
            // ---- S^T = K Q^T : st0/st1 cover keys {0..31},{32..63} ----
            f32x16 st0 = {}, st1 = {};
            __builtin_amdgcn_s_setprio(1);
            #pragma unroll
            for (int kt = 0; kt < 12; ++kt) {
                bf16x8 ak0 = *(bf16x8*)&Ks[lane31][kt * 16 + hi8];
                bf16x8 ak1 = *(bf16x8*)&Ks[32 + lane31][kt * 16 + hi8];
                st0 = __builtin_amdgcn_mfma_f32_32x32x16_bf16(ak0, aq[kt], st0, 0, 0, 0);
                st1 = __builtin_amdgcn_mfma_f32_32x32x16_bf16(ak1, aq[kt], st1, 0, 0, 0);
            }
            __builtin_amdgcn_s_setprio(0);

            // ---- scalarize + mask + tile max (key = ksub*32 + (r&3)+8*(r>>2)+4*hi) ----
            const bool dm = (s0 + 63 > q0 + w * 32);
            float sv0[16], sv1[16];
            float mt = -1e30f;
            #pragma unroll
            for (int r = 0; r < 16; ++r) {
                float a0 = st0[r] * rscale;
                float a1 = st1[r] * rscale;
                if (dm) {
                    int kr = (r & 3) + 8 * (r >> 2) + hi4;
                    if (s0 + kr > qglob)      a0 = -1e30f;
                    if (s0 + 32 + kr > qglob) a1 = -1e30f;
                }
                sv0[r] = a0; sv1[r] = a1;
                mt = fmaxf(mt, fmaxf(a0, a1));
            }
            mt = fmaxf(mt, __shfl_xor(mt, 32, 64));

            // ---- always-rescale online softmax ----
            float mn = fmaxf(m_i, mt);
            float al = __expf(m_i - mn);
            m_i = mn;

            // ---- P^T -> wave-private LDS ----
            float rsum = 0.f;
            #pragma unroll
            for (int g = 0; g < 4; ++g) {
                bf16x4 pr;
                #pragma unroll
                for (int j = 0; j < 4; ++j) {
                    __bf16 pb = (__bf16)__expf(sv0[g * 4 + j] - mn);
                    pr[j] = pb;
                    rsum += (float)pb;
                }
                *(bf16x4*)&PsT[w][lane31][g * 8 + hi4] = pr;
            }
            #pragma unroll
            for (int g = 0; g < 4; ++g) {
                bf16x4 pr;
                #pragma unroll
                for (int j = 0; j < 4; ++j) {
                    __bf16 pb = (__bf16)__expf(sv1[g * 4 + j] - mn);
                    pr[j] = pb;
                    rsum += (float)pb;
                }
                *(bf16x4*)&PsT[w][lane31][32 + g * 8 + hi4] = pr;
            }
            rsum += __shfl_xor(rsum, 32, 64);
            l_i = l_i * al + rsum;
            #pragma unroll
            for (int nb = 0; nb < 4; ++nb) Of[nb] *= al;

            // ---- O^T += Vt P^T (A = Vt rows = hd, B = P^T cols = q) ----
            __builtin_amdgcn_s_setprio(1);
            #pragma unroll
            for (int kblk = 0; kblk < 4; ++kblk) {
                bf16x8 bp = *(bf16x8*)&PsT[w][lane31][kblk * 16 + hi8];
                #pragma unroll
                for (int nb = 0; nb < 4; ++nb) {
                    bf16x8 av = *(bf16x8*)&Vt[nb * 32 + lane31][kblk * 16 + hi8];
                    Of[nb] = __builtin_amdgcn_mfma_f32_32x32x16_bf16(av, bp, Of[nb], 0, 0, 0);
                }
            }
            __builtin_amdgcn_s_setprio(0);
        }
    }

    // ---- write partials: O row q = w*32+lane31, cols hd = nb*32 + g*8 + hi*4 + j ----
    const int p = hb * 40 + pbase_qt(qt) + sp;
    __bf16* ob = opart + (size_t)p * (128 * 128) + (size_t)(w * 32 + lane31) * 128;
    #pragma unroll
    for (int nb = 0; nb < 4; ++nb)
        #pragma unroll
        for (int g = 0; g < 4; ++g) {
            bf16x4 o4;
            #pragma unroll
            for (int j = 0; j < 4; ++j) o4[j] = (__bf16)Of[nb][g * 4 + j];
            *(bf16x4*)(ob + nb * 32 + g * 8 + hi4) = o4;
        }
    if (hi == 0) {
        mlpart[(size_t)p * 256 + w * 32 + lane31]       = m_i;
        mlpart[(size_t)p * 256 + 128 + w * 32 + lane31] = l_i;
    }
}

// ============ combine split partials -> aob (bf16) =========================
__global__ __launch_bounds__(256)
void attn_reduce(const __bf16* __restrict__ opart, const float* __restrict__ mlpart,
                 __bf16* __restrict__ aob) {
    const int qt = blockIdx.x;                // 0..15 (q-tiles of 128)
    const int hb = blockIdx.y;
    const int h  = hb & (NH - 1);
    const int b  = hb >> 4;
    const int nsp = (qt >> 2) + 1;
    const int p0  = hb * 40 + pbase_qt(qt);
    const int tid = threadIdx.x;
    const int ql  = tid >> 1;                 // 0..127
    const int cg  = (tid & 1) * 64;

    float M = -1e30f;
    for (int s = 0; s < nsp; ++s)
        M = fmaxf(M, mlpart[(size_t)(p0 + s) * 256 + ql]);
    float L = 0.f;
    float acc[64];
    #pragma unroll
    for (int j = 0; j < 64; ++j) acc[j] = 0.f;
    for (int s = 0; s < nsp; ++s) {
        float ms = mlpart[(size_t)(p0 + s) * 256 + ql];
        float ls = mlpart[(size_t)(p0 + s) * 256 + 128 + ql];
        float sc = __expf(ms - M);
        L += ls * sc;
        const __bf16* op = opart + (size_t)(p0 + s) * (128 * 128) + (size_t)ql * 128 + cg;
        #pragma unroll
        for (int j8 = 0; j8 < 8; ++j8) {
            bf16x8 v = *(const bf16x8*)(op + j8 * 8);
            #pragma unroll
            for (int e = 0; e < 8; ++e) acc[j8 * 8 + e] += sc * (float)v[e];
        }
    }
    float invL = 1.0f / L;
    __bf16* outp = aob + ((size_t)(b * Tt + qt * 128 + ql)) * D + h * HD + cg;
    #pragma unroll
    for (int j8 = 0; j8 < 8; ++j8) {
        bf16x8 v;
        #pragma unroll
        for (int e = 0; e < 8; ++e) v[e] = (__bf16)(acc[j8 * 8 + e] * invL);
        *(bf16x8*)(outp + j8 * 8) = v;
    }
}

extern "C" void kernel_launch(void* const* d_in, const int* in_sizes, int n_in,
                              void* d_out, int out_size, void* d_ws, size_t ws_size,
                              hipStream_t stream) {
    const float* x    = (const float*)d_in[0];
    const float* Wkv  = (const float*)d_in[1];
    const float* Wkup = (const float*)d_in[2];
    const float* Wvup = (const float*)d_in[3];
    const float* Wq   = (const float*)d_in[4];
    const float* Wqr  = (const float*)d_in[5];
    const float* Wkr  = (const float*)d_in[6];
    const float* Wo   = (const float*)d_in[7];

    float* out0 = (float*)d_out;                     // (4096, 2048)
    float* out1 = out0 + (size_t)ROWS * D;           // (4096, 576) entry

    // ---- persistent buffers ----
    char* wsb = (char*)d_ws;
    __bf16* qext = (__bf16*)wsb;  wsb += (size_t)ROWS * LDX * 2;   // 17.8 MB
    __bf16* kext = (__bf16*)wsb;  wsb += (size_t)ROWS * LDX * 2;   // 17.8 MB
    __bf16* vtb  = (__bf16*)wsb;  wsb += (size_t)ROWS * D   * 2;   // 16.8 MB
    __bf16* aob  = (__bf16*)wsb;  wsb += (size_t)ROWS * D   * 2;   // 16.8 MB
    __bf16* WoT  = (__bf16*)wsb;  wsb += (size_t)D * D * 2;        //  8.4 MB

    // ---- phase-1 scratch (dead before attention) / attention partials ----
    char* scratch = wsb;
    __bf16* xb    = (__bf16*)scratch;                        // 16.8 MB
    __bf16* vb    = (__bf16*)(scratch + 16777216);           // 16.8 MB
    __bf16* ckvb  = (__bf16*)(scratch + 33554432);           //  4.2 MB
    __bf16* WkvT  = (__bf16*)(scratch + 37748736);           //  2.1 MB  }-- contiguous:
    __bf16* WqxT  = (__bf16*)(scratch + 39845888);           //  8.9 MB  }   [Wkv|Wq|Wqr]^T
    __bf16* KupxT = (__bf16*)(scratch + 48758784);           //  2.2 MB  }-- contiguous:
    __bf16* WvupT = (__bf16*)(scratch + 50987008);           //  2.1 MB  }   [Kup|Wkr|Wvup]^T
    // attention-phase aliases (overlay OK: all above dead by then)
    __bf16* opart  = (__bf16*)scratch;                       // 1280*32KB = 41.9 MB
    float*  mlpart = (float*)(scratch + (size_t)1280 * 128 * 128 * 2);  // 1.3 MB

    dim3 blk(256);

    // --- merged staging: x convert + all weight transposes (1 launch) ---
    stage_all<<<dim3(2048 + 2856), blk, 0, stream>>>(
        x, Wkv, Wq, Wqr, Wkup, Wkr, Wvup, Wo,
        xb, WkvT, WqxT, KupxT, WvupT, WoT);

    // --- GEMM1: xb @ [Wkv | Wq | Wqr]^T (N=2688, K=2048) ---
    //   cols 0..511   -> entry f32 (ldc 576) + ckvb bf16 (ldc 512)
    //   cols 512..2687-> qext bf16 (ldc LDX)
    gemm_split<true><<<dim3(2688 / 128, ROWS / 128), blk, 0, stream>>>(
        xb, WkvT, out1, ckvb, qext, 576, DC, LDX, 512, ROWS, D);

    // --- GEMM2: ckvb @ [Wkup | Wkr | Wvup]^T (N=4224, K=512) ---
    //   cols 0..2175  -> kext bf16 (ldc LDX)
    //   cols 2176..4223 -> vb bf16 (ldc D)
    gemm_split<false><<<dim3(4224 / 128, ROWS / 128), blk, 0, stream>>>(
        ckvb, KupxT, (float*)nullptr, kext, vb, 0, LDX, D, 2176, ROWS, DC);

    // --- rope both ext buffers (merged; kext half also fills entry cols) ---
    rope2<<<(2 * ROWS * 32 + 255) / 256, blk, 0, stream>>>(qext, kext, out1);

    // --- V transpose ---
    transpose_v<<<dim3(Tt / 64, D / 64, Bb), blk, 0, stream>>>(vb, vtb);

    // --- attention: split-KV (q-tile 128) + reduce ---
    attn_split<<<dim3(4, Tt / 128, NH * Bb), blk, 0, stream>>>(
        qext, kext, vtb, opart, mlpart);
    attn_reduce<<<dim3(Tt / 128, NH * Bb), blk, 0, stream>>>(opart, mlpart, aob);

    // --- out0 = ao @ Wo ---
    gemm_bt<true, false><<<dim3(D / 128, ROWS / 128), blk, 0, stream>>>(
        aob, WoT, out0, (__bf16*)nullptr, ROWS, D, D, 0);
}